// Round 8
// baseline (539.320 us; speedup 1.0000x reference)
//
#include <hip/hip_runtime.h>
#include <hip/hip_bf16.h>
#include <math.h>

typedef __bf16 bf16;
typedef bf16 bf16x8 __attribute__((ext_vector_type(8)));
typedef bf16 bf16x4 __attribute__((ext_vector_type(4)));
typedef float f32x4 __attribute__((ext_vector_type(4)));

#define ROWS 8192      // B*S = 4*2048
#define EMB  1024
#define NH   16
#define HD   64
#define FFN  4096
#define QKVN 3072
#define SEQ  2048

// async global->LDS, 16B per lane; LDS dest is wave-uniform base + lane*16
__device__ __forceinline__ void gl2lds16(const bf16* g, bf16* l) {
  __builtin_amdgcn_global_load_lds((const __attribute__((address_space(1))) void*)g,
                                   (__attribute__((address_space(3))) void*)l, 16, 0, 0);
}

// ---------------------------------------------------------------------------
// Transpose-cast: W [K][N] fp32 -> Wt [N][K] bf16 (times scale).
// grid (N/32, K/32), 256 thr.
// ---------------------------------------------------------------------------
__global__ void transpose_cast(const float* __restrict__ W, bf16* __restrict__ Wt,
                               int K, int N, float scale) {
  __shared__ float tile[32][33];
  const int n0 = blockIdx.x * 32, k0 = blockIdx.y * 32;
  const int tx = threadIdx.x & 31, ty = threadIdx.x >> 5;  // ty 0..7
#pragma unroll
  for (int i = 0; i < 32; i += 8)
    tile[ty + i][tx] = W[(size_t)(k0 + ty + i) * N + n0 + tx];
  __syncthreads();
#pragma unroll
  for (int i = 0; i < 32; i += 8)
    Wt[(size_t)(n0 + ty + i) * K + k0 + tx] = (bf16)(tile[tx][ty + i] * scale);
}

// ---------------------------------------------------------------------------
// Batched 1024x1024 transpose-cast: z selects {Wq,Wk,Wv,Wo}; destinations are
// contiguous in the workspace (wqkv_t then wo_t), so dst = base + z*EMB*EMB.
// Wq folds the 1/8 attention scale.  grid (32, 32, 4), 256 thr.
// ---------------------------------------------------------------------------
__global__ void transpose_cast4(const float* __restrict__ W0, const float* __restrict__ W1,
                                const float* __restrict__ W2, const float* __restrict__ W3,
                                bf16* __restrict__ dst) {
  __shared__ float tile[32][33];
  const int z = blockIdx.z;
  const float* W = (z == 0) ? W0 : (z == 1) ? W1 : (z == 2) ? W2 : W3;
  const float scale = (z == 0) ? 0.125f : 1.0f;
  bf16* Wt = dst + (size_t)z * EMB * EMB;
  const int n0 = blockIdx.x * 32, k0 = blockIdx.y * 32;
  const int tx = threadIdx.x & 31, ty = threadIdx.x >> 5;
#pragma unroll
  for (int i = 0; i < 32; i += 8)
    tile[ty + i][tx] = W[(size_t)(k0 + ty + i) * EMB + n0 + tx];
  __syncthreads();
#pragma unroll
  for (int i = 0; i < 32; i += 8)
    Wt[(size_t)(n0 + ty + i) * EMB + k0 + tx] = (bf16)(tile[tx][ty + i] * scale);
}

// ---------------------------------------------------------------------------
// V transpose: qkv V-part [b*2048+s][2048 + h*64 + d] -> vt[(bh*64+d)*2048+s]
// grid (64 s-tiles, 2 d-tiles, 64 bh), 256 thr, 32x32 tiles.
// ---------------------------------------------------------------------------
__global__ void v_transpose(const bf16* __restrict__ qkv, bf16* __restrict__ vt) {
  __shared__ bf16 tile[32][33];
  const int s0 = blockIdx.x * 32, d0 = blockIdx.y * 32, bh = blockIdx.z;
  const int b = bh >> 4, h = bh & 15;
  const int tx = threadIdx.x & 31, ty = threadIdx.x >> 5;
#pragma unroll
  for (int i = 0; i < 32; i += 8)
    tile[ty + i][tx] = qkv[(size_t)(b * SEQ + s0 + ty + i) * QKVN + 2 * EMB + h * HD + d0 + tx];
  __syncthreads();
#pragma unroll
  for (int i = 0; i < 32; i += 8)
    vt[(size_t)(bh * HD + d0 + ty + i) * SEQ + s0 + tx] = tile[tx][ty + i];
}

// ---------------------------------------------------------------------------
// LayerNorm fp32 -> bf16, wave-per-row (no LDS, no barriers, no serial lane).
// Block 256 thr = 4 waves = 4 rows; 16 f32/lane; butterfly shfl_xor reduce.
// grid ROWS/4.
// ---------------------------------------------------------------------------
__global__ __launch_bounds__(256) void layernorm_bf16(
    const float* __restrict__ x, const float* __restrict__ g,
    const float* __restrict__ b, bf16* __restrict__ out) {
  const int row = blockIdx.x * 4 + (threadIdx.x >> 6);
  const int lane = threadIdx.x & 63;
  const float4* xr = (const float4*)(x + (size_t)row * EMB);
  float4 v[4];
  float s = 0.f, ss = 0.f;
#pragma unroll
  for (int k = 0; k < 4; k++) {
    v[k] = xr[lane + 64 * k];
    s += v[k].x + v[k].y + v[k].z + v[k].w;
    ss += v[k].x * v[k].x + v[k].y * v[k].y + v[k].z * v[k].z + v[k].w * v[k].w;
  }
#pragma unroll
  for (int off = 32; off; off >>= 1) {
    s += __shfl_xor(s, off);
    ss += __shfl_xor(ss, off);
  }
  const float mu = s * (1.0f / EMB);
  const float rs = rsqrtf(ss * (1.0f / EMB) - mu * mu + 1e-5f);
  bf16* orow = out + (size_t)row * EMB;
#pragma unroll
  for (int k = 0; k < 4; k++) {
    const float4 gv = ((const float4*)g)[lane + 64 * k];
    const float4 bv = ((const float4*)b)[lane + 64 * k];
    bf16x4 o;
    o[0] = (bf16)((v[k].x - mu) * rs * gv.x + bv.x);
    o[1] = (bf16)((v[k].y - mu) * rs * gv.y + bv.y);
    o[2] = (bf16)((v[k].z - mu) * rs * gv.z + bv.z);
    o[3] = (bf16)((v[k].w - mu) * rs * gv.w + bv.w);
    *(bf16x4*)(orow + (size_t)(lane + 64 * k) * 4) = o;
  }
}

// ---------------------------------------------------------------------------
// GEMM: C[M][N] = A[M][K] (bf16 rm) * Bt[N][K]^T (bf16), global_load_lds stage
// 128x128 tile, BK=64, 4 waves.  LDS XOR-swizzled (chunk c of row r at c^(r&7))
// -> 0 measured bank conflicts.  (m97 structure — engine frozen; 8-phase
// reconstructions measured slower.)
// XCD-aware decode: xcd = lin%8 owns m-tiles [xcd*8, xcd*8+8); within an XCD
// the 8 m-tiles cycle fastest (sharing the B panel in that XCD's L2) and the
// per-XCD A slice (2 MB) stays L2-resident across the n sweep.
// Epilogues: 0=bf16  1=+resid f32  2=+bias,GELU(tanh) bf16  3=+bias+resid f32
// ---------------------------------------------------------------------------
template <int EPI, int N_, int K_>
__global__ __launch_bounds__(256, 2) void gemm_bt(
    const bf16* __restrict__ A, const bf16* __restrict__ Bt, void* __restrict__ C,
    const float* __restrict__ bias, const float* __restrict__ resid) {
  constexpr int N = N_, K = K_;
  __shared__ __align__(16) bf16 As[128 * 64];
  __shared__ __align__(16) bf16 Bs[128 * 64];
  const int tid = threadIdx.x;
  const int lane = tid & 63;
  const int wave = tid >> 6;
  const int wm = (wave >> 1) * 64;
  const int wn = (wave & 1) * 64;
  constexpr int tn = N / 128;
  const int lin = blockIdx.y * tn + blockIdx.x;
  const int xcd = lin & 7;             // dispatch round-robin heuristic
  const int idx = lin >> 3;
  const int m0 = (xcd * 8 + (idx & 7)) * 128;   // requires gridDim.y == 64
  const int n0 = (idx >> 3) * 128;
  const int quad = lane >> 4;
  const int l16 = lane & 15;
  const int srow8 = lane >> 3;                   // 0..7
  const int scol = ((lane & 7) ^ srow8) * 8;     // swizzled global col (elems)
  const int xr = l16 & 7;                        // read-side XOR key

  // staging base pointers (lane-fixed); k-advance by +64 elems per iter
  const bf16* ap = A + (size_t)(m0 + wave * 32 + srow8) * K + scol;
  const bf16* bp = Bt + (size_t)(n0 + wave * 32 + srow8) * K + scol;
  bf16* const as0 = &As[wave * 32 * 64];
  bf16* const bs0 = &Bs[wave * 32 * 64];

  f32x4 acc[4][4] = {};

  for (int kt = 0; kt < K; kt += 64) {
    __syncthreads();
#pragma unroll
    for (int q = 0; q < 4; q++) {
      gl2lds16(ap + q * 8 * K, as0 + q * 8 * 64);
      gl2lds16(bp + q * 8 * K, bs0 + q * 8 * 64);
    }
    ap += 64;
    bp += 64;
    __syncthreads();
#pragma unroll
    for (int h = 0; h < 2; h++) {
      const int cp = ((h * 4 + quad) ^ xr) * 8;
      bf16x8 af[4], bfr[4];
#pragma unroll
      for (int i = 0; i < 4; i++)
        af[i] = *(const bf16x8*)&As[(wm + i * 16 + l16) * 64 + cp];
#pragma unroll
      for (int j = 0; j < 4; j++)
        bfr[j] = *(const bf16x8*)&Bs[(wn + j * 16 + l16) * 64 + cp];
#pragma unroll
      for (int i = 0; i < 4; i++)
#pragma unroll
        for (int j = 0; j < 4; j++)
          acc[i][j] = __builtin_amdgcn_mfma_f32_16x16x32_bf16(af[i], bfr[j], acc[i][j], 0, 0, 0);
    }
  }

#pragma unroll
  for (int i = 0; i < 4; i++)
#pragma unroll
    for (int j = 0; j < 4; j++)
#pragma unroll
      for (int r = 0; r < 4; r++) {
        const int row = m0 + wm + i * 16 + quad * 4 + r;
        const int col = n0 + wn + j * 16 + l16;
        const size_t idx2 = (size_t)row * N + col;
        float v = acc[i][j][r];
        if (EPI == 0) {
          ((bf16*)C)[idx2] = (bf16)v;
        } else if (EPI == 1) {
          ((float*)C)[idx2] = v + resid[idx2];
        } else if (EPI == 2) {
          v += bias[col];
          // tanh-form GELU: max |delta| vs exact ~1e-3 << bf16 noise
          const float u = 1.5957691216f * (v + 0.044715f * v * v * v);
          v = v / (1.0f + __expf(-u));
          ((bf16*)C)[idx2] = (bf16)v;
        } else {
          ((float*)C)[idx2] = v + bias[col] + resid[idx2];
        }
      }
}

// ---------------------------------------------------------------------------
// Flash attention (causal), fixed-base softmax.  Q pre-scaled by 1/8.
// Q-tile 64 (4 waves), K-tile 64, q-tile pairing (31-p, p) -> 33 iters/block.
// 1D grid of 1024; decode xcd = bid%8 so all 16 blocks of one (b,h) land on
// one XCD (K/V 512 KB stays in that L2).
// T14 async-STAGE split (reg-staged K/V, same XOR-swizzled LDS layout as the
// old gl2lds path):
//   per iter: s_barrier | ds_write regs(kt) | issue global loads(kt+1)->regs
//             | lgkmcnt(0)+sched_barrier+s_barrier | compute(kt)
// Global-load latency spans the whole compute phase (~>1000 cyc), so the
// critical path only waits on the 4 ds_writes.  No __syncthreads anywhere in
// the loop -> the in-flight global loads are never drained at a barrier.
// Single-buffered LDS is safe: barrier-1 is only crossed after every wave's
// tile-(kt-1) ds_reads were consumed by MFMAs (lgkm drained by data deps).
// LDS 25.6 KB -> 6 blocks/CU; +16 VGPR for the staging regs.
// ---------------------------------------------------------------------------
__global__ __launch_bounds__(256, 6) void flash_attn(
    const bf16* __restrict__ qkv, const bf16* __restrict__ vt, bf16* __restrict__ out) {
  const int bid = blockIdx.x;
  const int xcd = bid & 7;
  const int idx = bid >> 3;            // 0..127
  const int pr = idx & 15;
  const int bh = xcd + ((idx >> 4) << 3);
  const int b = bh >> 4, h = bh & 15;
  const int tid = threadIdx.x;
  const int lane = tid & 63, wave = tid >> 6;
  const int quad = lane >> 4, l16 = lane & 15;

  __shared__ __align__(16) bf16 Ks[64 * 64];
  __shared__ __align__(16) bf16 Vts[64 * 64];   // [d][key]
  __shared__ __align__(16) bf16 Ps[4][16][72];

  const size_t rowbase = (size_t)b * SEQ;
  const int s8 = (lane >> 3) & 7;  // 0..7 staging row within 8-row group
  const int cs = ((lane & 7) ^ s8) * 8;          // swizzled fetch col (elems)
  const int xk = l16 & 7;                        // read-side XOR key
  const bf16* kbase = qkv + rowbase * QKVN + EMB + h * HD;
  const bf16* vbase = vt + (size_t)(bh * HD) * SEQ;

  // staging pointers for this lane (content chunk (lane&7)^s8 of its rows)
  const bf16* kp = kbase + (size_t)(wave * 8 + s8) * QKVN + cs;
  const bf16* vp = vbase + (size_t)(wave * 8 + s8) * SEQ + cs;
  // LDS elem dest: row (wave*8+s8), chunk position (lane&7)  == base+lane*8
  bf16* const kd0 = &Ks[(wave * 8) * 64 + lane * 8];
  bf16* const kd1 = &Ks[(32 + wave * 8) * 64 + lane * 8];
  bf16* const vd0 = &Vts[(wave * 8) * 64 + lane * 8];
  bf16* const vd1 = &Vts[(32 + wave * 8) * 64 + lane * 8];

  bf16x8 rk0, rk1, rv0, rv1;   // in-flight staging registers
#define LOAD_KV(T)                                                             \
  rk0 = *(const bf16x8*)(kp + (size_t)(T) * 64 * QKVN);                        \
  rk1 = *(const bf16x8*)(kp + ((size_t)(T) * 64 + 32) * QKVN);                 \
  rv0 = *(const bf16x8*)(vp + (T) * 64);                                       \
  rv1 = *(const bf16x8*)(vp + (size_t)32 * SEQ + (T) * 64);

#pragma unroll 1
  for (int half = 0; half < 2; half++) {
    const int qt = half ? pr : 31 - pr;           // heavy tile first
    const int qrow_a = qt * 64 + wave * 16 + l16;
    const bf16* qptr = qkv + (rowbase + qrow_a) * QKVN + h * HD;
    const bf16x8 qf0 = *(const bf16x8*)(qptr + quad * 8);
    const bf16x8 qf1 = *(const bf16x8*)(qptr + 32 + quad * 8);
    f32x4 o0 = {}, o1 = {}, o2 = {}, o3 = {};
    f32x4 lsum = {};
    const int qrow_c = qt * 64 + wave * 16 + quad * 4;

    LOAD_KV(0);   // prologue: issue tile-0 loads

#pragma unroll 1
    for (int kt = 0; kt <= qt; kt++) {
      // barrier-1: all waves consumed tile kt-1 from LDS (reads drained by
      // MFMA data deps); safe to overwrite.
      __builtin_amdgcn_sched_barrier(0);
      __builtin_amdgcn_s_barrier();
      // write tile kt (compiler inserts the vmcnt wait for rk/rv here)
      *(bf16x8*)kd0 = rk0;
      *(bf16x8*)kd1 = rk1;
      *(bf16x8*)vd0 = rv0;
      *(bf16x8*)vd1 = rv1;
      // issue next tile's loads; latency hides under this iteration's compute
      if (kt < qt) { LOAD_KV(kt + 1); }
      // barrier-2: ds_writes visible to all waves
      asm volatile("s_waitcnt lgkmcnt(0)");
      __builtin_amdgcn_sched_barrier(0);
      __builtin_amdgcn_s_barrier();

      if (kt < qt) {
        // interior tiles: fully unmasked, no compares, no cross-lane reduce
#pragma unroll
        for (int j = 0; j < 4; j++) {
          const int rr = (j * 16 + l16) * 64;
          const bf16x8 kf0 = *(const bf16x8*)&Ks[rr + (quad ^ xk) * 8];
          const bf16x8 kf1 = *(const bf16x8*)&Ks[rr + ((4 + quad) ^ xk) * 8];
          f32x4 a = {};
          a = __builtin_amdgcn_mfma_f32_16x16x32_bf16(qf0, kf0, a, 0, 0, 0);
          a = __builtin_amdgcn_mfma_f32_16x16x32_bf16(qf1, kf1, a, 0, 0, 0);
#pragma unroll
          for (int r = 0; r < 4; r++) {
            const float pj = __expf(a[r]);
            lsum[r] += pj;
            Ps[wave][quad * 4 + r][j * 16 + l16] = (bf16)pj;
          }
        }
      } else {
        // diagonal tile: j<wave unmasked, j==wave partial mask, j>wave all 0
#pragma unroll
        for (int j = 0; j < 4; j++) {
          if (j > wave) {
#pragma unroll
            for (int r = 0; r < 4; r++)
              Ps[wave][quad * 4 + r][j * 16 + l16] = (bf16)0.0f;
          } else {
            const int rr = (j * 16 + l16) * 64;
            const bf16x8 kf0 = *(const bf16x8*)&Ks[rr + (quad ^ xk) * 8];
            const bf16x8 kf1 = *(const bf16x8*)&Ks[rr + ((4 + quad) ^ xk) * 8];
            f32x4 a = {};
            a = __builtin_amdgcn_mfma_f32_16x16x32_bf16(qf0, kf0, a, 0, 0, 0);
            a = __builtin_amdgcn_mfma_f32_16x16x32_bf16(qf1, kf1, a, 0, 0, 0);
            if (j == wave) {
#pragma unroll
              for (int r = 0; r < 4; r++) {
                const float v = (l16 > quad * 4 + r) ? -INFINITY : a[r];
                const float pj = __expf(v);
                lsum[r] += pj;
                Ps[wave][quad * 4 + r][j * 16 + l16] = (bf16)pj;
              }
            } else {
#pragma unroll
              for (int r = 0; r < 4; r++) {
                const float pj = __expf(a[r]);
                lsum[r] += pj;
                Ps[wave][quad * 4 + r][j * 16 + l16] = (bf16)pj;
              }
            }
          }
        }
      }
      // Ps write->read is same-wave; lgkmcnt ordering suffices (no barrier)

      const bf16x8 af0 = *(const bf16x8*)&Ps[wave][l16][quad * 8];
      const bf16x8 af1 = *(const bf16x8*)&Ps[wave][l16][32 + quad * 8];
#pragma unroll
      for (int j = 0; j < 4; j++) {
        const int rr = (j * 16 + l16) * 64;
        const bf16x8 vf0 = *(const bf16x8*)&Vts[rr + (quad ^ xk) * 8];
        const bf16x8 vf1 = *(const bf16x8*)&Vts[rr + ((4 + quad) ^ xk) * 8];
        f32x4& oj = (j == 0) ? o0 : (j == 1) ? o1 : (j == 2) ? o2 : o3;
        oj = __builtin_amdgcn_mfma_f32_16x16x32_bf16(af0, vf0, oj, 0, 0, 0);
        oj = __builtin_amdgcn_mfma_f32_16x16x32_bf16(af1, vf1, oj, 0, 0, 0);
      }
    }

    // final: reduce l across the 16 columns (lanes of the l16 group), store
#pragma unroll
    for (int r = 0; r < 4; r++) {
      float ls = lsum[r];
      ls += __shfl_xor(ls, 1);
      ls += __shfl_xor(ls, 2);
      ls += __shfl_xor(ls, 4);
      ls += __shfl_xor(ls, 8);
      const float iv = 1.0f / ls;
      bf16* op = out + (rowbase + qrow_c + r) * EMB + h * HD;
      op[0 + l16] = (bf16)(o0[r] * iv);
      op[16 + l16] = (bf16)(o1[r] * iv);
      op[32 + l16] = (bf16)(o2[r] * iv);
      op[48 + l16] = (bf16)(o3[r] * iv);
    }
  }
#undef LOAD_KV
}

// ---------------------------------------------------------------------------
extern "C" void kernel_launch(void* const* d_in, const int* in_sizes, int n_in,
                              void* d_out, int out_size, void* d_ws, size_t ws_size,
                              hipStream_t stream) {
  const float* x     = (const float*)d_in[0];
  const float* Wq    = (const float*)d_in[1];
  const float* Wk    = (const float*)d_in[2];
  const float* Wv    = (const float*)d_in[3];
  const float* Wo    = (const float*)d_in[4];
  const float* ln1_g = (const float*)d_in[5];
  const float* ln1_b = (const float*)d_in[6];
  const float* ln2_g = (const float*)d_in[7];
  const float* ln2_b = (const float*)d_in[8];
  const float* W1    = (const float*)d_in[9];
  const float* b1    = (const float*)d_in[10];
  const float* W2    = (const float*)d_in[11];
  const float* b2    = (const float*)d_in[12];
  float* out = (float*)d_out;  // doubles as x2 (post-attention residual state)

  bf16* p = (bf16*)d_ws;
  bf16* wqkv_t = p;                 p += (size_t)QKVN * EMB;   // [3072][1024]
  bf16* wo_t   = p;                 p += (size_t)EMB * EMB;    // [1024][1024]
  bf16* w1_t   = p;                 p += (size_t)FFN * EMB;    // [4096][1024]
  bf16* w2_t   = p;                 p += (size_t)EMB * FFN;    // [1024][4096]
  bf16* h      = p;                 p += (size_t)ROWS * EMB;   // LN out; aliased as vt
  bf16* qkv    = p;                 p += (size_t)ROWS * QKVN;  // [8192][3072]
  bf16* attn_o = p;                 p += (size_t)ROWS * EMB;   // [8192][1024]
  bf16* ffn1   = p;                 /* [8192][4096] */
  bf16* vt     = h;  // alias: h (LN1 out) is dead once QKV GEMM completes

  // 1) weight transpose-casts.  Wq/Wk/Wv/Wo in ONE launch (contiguous dests:
  //    wqkv_t then wo_t); Wq folds the 1/8 attention scale.
  transpose_cast4<<<dim3(32, 32, 4), 256, 0, stream>>>(Wq, Wk, Wv, Wo, wqkv_t);
  transpose_cast<<<dim3(128, 32), 256, 0, stream>>>(W1, w1_t, EMB, FFN, 1.0f);
  transpose_cast<<<dim3(32, 128), 256, 0, stream>>>(W2, w2_t, FFN, EMB, 1.0f);

  // 2) LN1 (wave-per-row)
  layernorm_bf16<<<ROWS / 4, 256, 0, stream>>>(x, ln1_g, ln1_b, h);

  // 3) fused QKV projection
  gemm_bt<0, QKVN, EMB><<<dim3(QKVN / 128, ROWS / 128), 256, 0, stream>>>(
      h, wqkv_t, qkv, nullptr, nullptr);

  // 4) V transpose (h is dead now; vt aliases it)
  v_transpose<<<dim3(SEQ / 32, HD / 32, 64), 256, 0, stream>>>(qkv, vt);

  // 5) causal flash attention (paired q-tiles, T14 async-stage K/V)
  flash_attn<<<1024, 256, 0, stream>>>(qkv, vt, attn_o);

  // 6) output projection + residual -> x2 (in d_out)
  gemm_bt<1, EMB, EMB><<<dim3(EMB / 128, ROWS / 128), 256, 0, stream>>>(
      attn_o, wo_t, out, nullptr, x);

  // 7) LN2 (overwrites vt alias — flash is done)
  layernorm_bf16<<<ROWS / 4, 256, 0, stream>>>(out, ln2_g, ln2_b, h);

  // 8) FFN up + GELU (tanh form)
  gemm_bt<2, FFN, EMB><<<dim3(FFN / 128, ROWS / 128), 256, 0, stream>>>(
      h, w1_t, ffn1, b1, nullptr);

  // 9) FFN down + bias + residual -> final out
  gemm_bt<3, EMB, FFN><<<dim3(EMB / 128, ROWS / 128), 256, 0, stream>>>(
      ffn1, w2_t, out, b2, out);
}

// Round 9
// 449.359 us; speedup vs baseline: 1.2002x; 1.2002x over previous
//
#include <hip/hip_runtime.h>
#include <hip/hip_bf16.h>
#include <math.h>

typedef __bf16 bf16;
typedef bf16 bf16x8 __attribute__((ext_vector_type(8)));
typedef bf16 bf16x4 __attribute__((ext_vector_type(4)));
typedef float f32x4 __attribute__((ext_vector_type(4)));

#define ROWS 8192      // B*S = 4*2048
#define EMB  1024
#define NH   16
#define HD   64
#define FFN  4096
#define QKVN 3072
#define SEQ  2048

// async global->LDS, 16B per lane; LDS dest is wave-uniform base + lane*16
__device__ __forceinline__ void gl2lds16(const bf16* g, bf16* l) {
  __builtin_amdgcn_global_load_lds((const __attribute__((address_space(1))) void*)g,
                                   (__attribute__((address_space(3))) void*)l, 16, 0, 0);
}

// ---------------------------------------------------------------------------
// Transpose-cast: W [K][N] fp32 -> Wt [N][K] bf16 (times scale).
// grid (N/32, K/32), 256 thr.
// ---------------------------------------------------------------------------
__global__ void transpose_cast(const float* __restrict__ W, bf16* __restrict__ Wt,
                               int K, int N, float scale) {
  __shared__ float tile[32][33];
  const int n0 = blockIdx.x * 32, k0 = blockIdx.y * 32;
  const int tx = threadIdx.x & 31, ty = threadIdx.x >> 5;  // ty 0..7
#pragma unroll
  for (int i = 0; i < 32; i += 8)
    tile[ty + i][tx] = W[(size_t)(k0 + ty + i) * N + n0 + tx];
  __syncthreads();
#pragma unroll
  for (int i = 0; i < 32; i += 8)
    Wt[(size_t)(n0 + ty + i) * K + k0 + tx] = (bf16)(tile[tx][ty + i] * scale);
}

// ---------------------------------------------------------------------------
// Batched 1024x1024 transpose-cast: z selects {Wq,Wk,Wv,Wo}; destinations are
// contiguous in the workspace (wqkv_t then wo_t), so dst = base + z*EMB*EMB.
// Wq folds the 1/8 attention scale.  grid (32, 32, 4), 256 thr.
// ---------------------------------------------------------------------------
__global__ void transpose_cast4(const float* __restrict__ W0, const float* __restrict__ W1,
                                const float* __restrict__ W2, const float* __restrict__ W3,
                                bf16* __restrict__ dst) {
  __shared__ float tile[32][33];
  const int z = blockIdx.z;
  const float* W = (z == 0) ? W0 : (z == 1) ? W1 : (z == 2) ? W2 : W3;
  const float scale = (z == 0) ? 0.125f : 1.0f;
  bf16* Wt = dst + (size_t)z * EMB * EMB;
  const int n0 = blockIdx.x * 32, k0 = blockIdx.y * 32;
  const int tx = threadIdx.x & 31, ty = threadIdx.x >> 5;
#pragma unroll
  for (int i = 0; i < 32; i += 8)
    tile[ty + i][tx] = W[(size_t)(k0 + ty + i) * EMB + n0 + tx];
  __syncthreads();
#pragma unroll
  for (int i = 0; i < 32; i += 8)
    Wt[(size_t)(n0 + ty + i) * EMB + k0 + tx] = (bf16)(tile[tx][ty + i] * scale);
}

// ---------------------------------------------------------------------------
// V transpose: qkv V-part [b*2048+s][2048 + h*64 + d] -> vt[(bh*64+d)*2048+s]
// grid (64 s-tiles, 2 d-tiles, 64 bh), 256 thr, 32x32 tiles.
// (R5 tried fusing this into the QKV epilogue: scattered 8-B stores regressed
//  total by 10 us -> kept standalone/coalesced.)
// ---------------------------------------------------------------------------
__global__ void v_transpose(const bf16* __restrict__ qkv, bf16* __restrict__ vt) {
  __shared__ bf16 tile[32][33];
  const int s0 = blockIdx.x * 32, d0 = blockIdx.y * 32, bh = blockIdx.z;
  const int b = bh >> 4, h = bh & 15;
  const int tx = threadIdx.x & 31, ty = threadIdx.x >> 5;
#pragma unroll
  for (int i = 0; i < 32; i += 8)
    tile[ty + i][tx] = qkv[(size_t)(b * SEQ + s0 + ty + i) * QKVN + 2 * EMB + h * HD + d0 + tx];
  __syncthreads();
#pragma unroll
  for (int i = 0; i < 32; i += 8)
    vt[(size_t)(bh * HD + d0 + ty + i) * SEQ + s0 + tx] = tile[tx][ty + i];
}

// ---------------------------------------------------------------------------
// LayerNorm fp32 -> bf16, wave-per-row (no LDS, no barriers, no serial lane).
// Block 256 thr = 4 waves = 4 rows; 16 f32/lane; butterfly shfl_xor reduce.
// grid ROWS/4.
// ---------------------------------------------------------------------------
__global__ __launch_bounds__(256) void layernorm_bf16(
    const float* __restrict__ x, const float* __restrict__ g,
    const float* __restrict__ b, bf16* __restrict__ out) {
  const int row = blockIdx.x * 4 + (threadIdx.x >> 6);
  const int lane = threadIdx.x & 63;
  const float4* xr = (const float4*)(x + (size_t)row * EMB);
  float4 v[4];
  float s = 0.f, ss = 0.f;
#pragma unroll
  for (int k = 0; k < 4; k++) {
    v[k] = xr[lane + 64 * k];
    s += v[k].x + v[k].y + v[k].z + v[k].w;
    ss += v[k].x * v[k].x + v[k].y * v[k].y + v[k].z * v[k].z + v[k].w * v[k].w;
  }
#pragma unroll
  for (int off = 32; off; off >>= 1) {
    s += __shfl_xor(s, off);
    ss += __shfl_xor(ss, off);
  }
  const float mu = s * (1.0f / EMB);
  const float rs = rsqrtf(ss * (1.0f / EMB) - mu * mu + 1e-5f);
  bf16* orow = out + (size_t)row * EMB;
#pragma unroll
  for (int k = 0; k < 4; k++) {
    const float4 gv = ((const float4*)g)[lane + 64 * k];
    const float4 bv = ((const float4*)b)[lane + 64 * k];
    bf16x4 o;
    o[0] = (bf16)((v[k].x - mu) * rs * gv.x + bv.x);
    o[1] = (bf16)((v[k].y - mu) * rs * gv.y + bv.y);
    o[2] = (bf16)((v[k].z - mu) * rs * gv.z + bv.z);
    o[3] = (bf16)((v[k].w - mu) * rs * gv.w + bv.w);
    *(bf16x4*)(orow + (size_t)(lane + 64 * k) * 4) = o;
  }
}

// ---------------------------------------------------------------------------
// GEMM: C[M][N] = A[M][K] (bf16 rm) * Bt[N][K]^T (bf16), global_load_lds stage
// 128x128 tile, BK=64, 4 waves.  LDS XOR-swizzled (chunk c of row r at c^(r&7))
// -> 0 measured bank conflicts.  ENGINE FROZEN at the m97 structure (~802 TF
// on FFN-down): two 8-phase/256-tile reconstructions measured slower (93 vs
// 85.7 us) -- going past this ceiling needs the verified 8-phase schedule
// file (intra-phase interleave + derived vmcnt), not a from-memory port.
// XCD-aware decode: xcd = lin%8 owns m-tiles [xcd*8, xcd*8+8); within an XCD
// the 8 m-tiles cycle fastest (sharing the B panel in that XCD's L2) and the
// per-XCD A slice (2 MB) stays L2-resident across the n sweep.
// Epilogues: 0=bf16  1=+resid f32  2=+bias,GELU(tanh) bf16  3=+bias+resid f32
// ---------------------------------------------------------------------------
template <int EPI, int N_, int K_>
__global__ __launch_bounds__(256, 2) void gemm_bt(
    const bf16* __restrict__ A, const bf16* __restrict__ Bt, void* __restrict__ C,
    const float* __restrict__ bias, const float* __restrict__ resid) {
  constexpr int N = N_, K = K_;
  __shared__ __align__(16) bf16 As[128 * 64];
  __shared__ __align__(16) bf16 Bs[128 * 64];
  const int tid = threadIdx.x;
  const int lane = tid & 63;
  const int wave = tid >> 6;
  const int wm = (wave >> 1) * 64;
  const int wn = (wave & 1) * 64;
  constexpr int tn = N / 128;
  const int lin = blockIdx.y * tn + blockIdx.x;
  const int xcd = lin & 7;             // dispatch round-robin heuristic
  const int idx = lin >> 3;
  const int m0 = (xcd * 8 + (idx & 7)) * 128;   // requires gridDim.y == 64
  const int n0 = (idx >> 3) * 128;
  const int quad = lane >> 4;
  const int l16 = lane & 15;
  const int srow8 = lane >> 3;                   // 0..7
  const int scol = ((lane & 7) ^ srow8) * 8;     // swizzled global col (elems)
  const int xr = l16 & 7;                        // read-side XOR key

  // staging base pointers (lane-fixed); k-advance by +64 elems per iter
  const bf16* ap = A + (size_t)(m0 + wave * 32 + srow8) * K + scol;
  const bf16* bp = Bt + (size_t)(n0 + wave * 32 + srow8) * K + scol;
  bf16* const as0 = &As[wave * 32 * 64];
  bf16* const bs0 = &Bs[wave * 32 * 64];

  f32x4 acc[4][4] = {};

  for (int kt = 0; kt < K; kt += 64) {
    __syncthreads();
#pragma unroll
    for (int q = 0; q < 4; q++) {
      gl2lds16(ap + q * 8 * K, as0 + q * 8 * 64);
      gl2lds16(bp + q * 8 * K, bs0 + q * 8 * 64);
    }
    ap += 64;
    bp += 64;
    __syncthreads();
#pragma unroll
    for (int h = 0; h < 2; h++) {
      const int cp = ((h * 4 + quad) ^ xr) * 8;
      bf16x8 af[4], bfr[4];
#pragma unroll
      for (int i = 0; i < 4; i++)
        af[i] = *(const bf16x8*)&As[(wm + i * 16 + l16) * 64 + cp];
#pragma unroll
      for (int j = 0; j < 4; j++)
        bfr[j] = *(const bf16x8*)&Bs[(wn + j * 16 + l16) * 64 + cp];
#pragma unroll
      for (int i = 0; i < 4; i++)
#pragma unroll
        for (int j = 0; j < 4; j++)
          acc[i][j] = __builtin_amdgcn_mfma_f32_16x16x32_bf16(af[i], bfr[j], acc[i][j], 0, 0, 0);
    }
  }

#pragma unroll
  for (int i = 0; i < 4; i++)
#pragma unroll
    for (int j = 0; j < 4; j++)
#pragma unroll
      for (int r = 0; r < 4; r++) {
        const int row = m0 + wm + i * 16 + quad * 4 + r;
        const int col = n0 + wn + j * 16 + l16;
        const size_t idx2 = (size_t)row * N + col;
        float v = acc[i][j][r];
        if (EPI == 0) {
          ((bf16*)C)[idx2] = (bf16)v;
        } else if (EPI == 1) {
          ((float*)C)[idx2] = v + resid[idx2];
        } else if (EPI == 2) {
          v += bias[col];
          // tanh-form GELU: max |delta| vs exact ~1e-3 << bf16 noise
          const float u = 1.5957691216f * (v + 0.044715f * v * v * v);
          v = v / (1.0f + __expf(-u));
          ((bf16*)C)[idx2] = (bf16)v;
        } else {
          ((float*)C)[idx2] = v + bias[col] + resid[idx2];
        }
      }
}

// ---------------------------------------------------------------------------
// Flash attention (causal), fixed-base softmax.  Q pre-scaled by 1/8.
// Q-tile 64 (4 waves), K-tile 64, q-tile pairing (31-p, p) -> 33 iters/block.
// 1D grid of 1024; decode xcd = bid%8 so all 16 blocks of one (b,h) land on
// one XCD (K/V 512 KB stays in that L2).  K/V staged via global_load_lds with
// XOR-swizzled fetch (chunk c of row r at c^(r&7)) -> conflict-free.
// 6 blocks/CU (LDS 25 KB).
// FROZEN: four pipelining attempts measured worse -- q-tile split (92us,
// iteration-balance loss), K-dbuf+V-direct (150us, exposed per-lane V-load
// latency), T14 reg-staging (122us, rk/rv spilled to scratch: 112MB phantom
// HBM writes).  This gl2lds form = 77.8us measured.
// ---------------------------------------------------------------------------
__global__ __launch_bounds__(256, 6) void flash_attn(
    const bf16* __restrict__ qkv, const bf16* __restrict__ vt, bf16* __restrict__ out) {
  const int bid = blockIdx.x;
  const int xcd = bid & 7;
  const int idx = bid >> 3;            // 0..127
  const int pr = idx & 15;
  const int bh = xcd + ((idx >> 4) << 3);
  const int b = bh >> 4, h = bh & 15;
  const int tid = threadIdx.x;
  const int lane = tid & 63, wave = tid >> 6;
  const int quad = lane >> 4, l16 = lane & 15;

  __shared__ __align__(16) bf16 Ks[64 * 64];
  __shared__ __align__(16) bf16 Vts[64 * 64];   // [d][key]
  __shared__ __align__(16) bf16 Ps[4][16][72];

  const size_t rowbase = (size_t)b * SEQ;
  const int s8 = (lane >> 3) & 7;  // 0..7 staging row within 8-row group
  const int cs = ((lane & 7) ^ s8) * 8;          // swizzled fetch col (elems)
  const int xk = l16 & 7;                        // read-side XOR key
  const bf16* kbase = qkv + rowbase * QKVN + EMB + h * HD;
  const bf16* vbase = vt + (size_t)(bh * HD) * SEQ;

#pragma unroll 1
  for (int half = 0; half < 2; half++) {
    const int qt = half ? pr : 31 - pr;           // heavy tile first
    const int qrow_a = qt * 64 + wave * 16 + l16;
    const bf16* qptr = qkv + (rowbase + qrow_a) * QKVN + h * HD;
    const bf16x8 qf0 = *(const bf16x8*)(qptr + quad * 8);
    const bf16x8 qf1 = *(const bf16x8*)(qptr + 32 + quad * 8);
    f32x4 o0 = {}, o1 = {}, o2 = {}, o3 = {};
    f32x4 lsum = {};
    const int qrow_c = qt * 64 + wave * 16 + quad * 4;

    // staging pointers for this wave (8 rows per gl2lds16 call)
    const bf16* kp = kbase + (size_t)(wave * 8 + s8) * QKVN + cs;
    const bf16* vp = vbase + (size_t)(wave * 8 + s8) * SEQ + cs;

#pragma unroll 1
    for (int kt = 0; kt <= qt; kt++) {
      __syncthreads();
      gl2lds16(kp + (size_t)kt * 64 * QKVN, &Ks[(wave * 8) * 64]);
      gl2lds16(kp + (size_t)(kt * 64 + 32) * QKVN, &Ks[(32 + wave * 8) * 64]);
      gl2lds16(vp + kt * 64, &Vts[(wave * 8) * 64]);
      gl2lds16(vp + (size_t)32 * SEQ + kt * 64, &Vts[(32 + wave * 8) * 64]);
      __syncthreads();

      if (kt < qt) {
        // interior tiles: fully unmasked, no compares, no cross-lane reduce
#pragma unroll
        for (int j = 0; j < 4; j++) {
          const int rr = (j * 16 + l16) * 64;
          const bf16x8 kf0 = *(const bf16x8*)&Ks[rr + (quad ^ xk) * 8];
          const bf16x8 kf1 = *(const bf16x8*)&Ks[rr + ((4 + quad) ^ xk) * 8];
          f32x4 a = {};
          a = __builtin_amdgcn_mfma_f32_16x16x32_bf16(qf0, kf0, a, 0, 0, 0);
          a = __builtin_amdgcn_mfma_f32_16x16x32_bf16(qf1, kf1, a, 0, 0, 0);
#pragma unroll
          for (int r = 0; r < 4; r++) {
            const float pj = __expf(a[r]);
            lsum[r] += pj;
            Ps[wave][quad * 4 + r][j * 16 + l16] = (bf16)pj;
          }
        }
      } else {
        // diagonal tile: j<wave unmasked, j==wave partial mask, j>wave all 0
#pragma unroll
        for (int j = 0; j < 4; j++) {
          if (j > wave) {
#pragma unroll
            for (int r = 0; r < 4; r++)
              Ps[wave][quad * 4 + r][j * 16 + l16] = (bf16)0.0f;
          } else {
            const int rr = (j * 16 + l16) * 64;
            const bf16x8 kf0 = *(const bf16x8*)&Ks[rr + (quad ^ xk) * 8];
            const bf16x8 kf1 = *(const bf16x8*)&Ks[rr + ((4 + quad) ^ xk) * 8];
            f32x4 a = {};
            a = __builtin_amdgcn_mfma_f32_16x16x32_bf16(qf0, kf0, a, 0, 0, 0);
            a = __builtin_amdgcn_mfma_f32_16x16x32_bf16(qf1, kf1, a, 0, 0, 0);
            if (j == wave) {
#pragma unroll
              for (int r = 0; r < 4; r++) {
                const float v = (l16 > quad * 4 + r) ? -INFINITY : a[r];
                const float pj = __expf(v);
                lsum[r] += pj;
                Ps[wave][quad * 4 + r][j * 16 + l16] = (bf16)pj;
              }
            } else {
#pragma unroll
              for (int r = 0; r < 4; r++) {
                const float pj = __expf(a[r]);
                lsum[r] += pj;
                Ps[wave][quad * 4 + r][j * 16 + l16] = (bf16)pj;
              }
            }
          }
        }
      }
      // Ps write->read is same-wave; lgkmcnt ordering suffices (no barrier)

      const bf16x8 af0 = *(const bf16x8*)&Ps[wave][l16][quad * 8];
      const bf16x8 af1 = *(const bf16x8*)&Ps[wave][l16][32 + quad * 8];
#pragma unroll
      for (int j = 0; j < 4; j++) {
        const int rr = (j * 16 + l16) * 64;
        const bf16x8 vf0 = *(const bf16x8*)&Vts[rr + (quad ^ xk) * 8];
        const bf16x8 vf1 = *(const bf16x8*)&Vts[rr + ((4 + quad) ^ xk) * 8];
        f32x4& oj = (j == 0) ? o0 : (j == 1) ? o1 : (j == 2) ? o2 : o3;
        oj = __builtin_amdgcn_mfma_f32_16x16x32_bf16(af0, vf0, oj, 0, 0, 0);
        oj = __builtin_amdgcn_mfma_f32_16x16x32_bf16(af1, vf1, oj, 0, 0, 0);
      }
    }

    // final: reduce l across the 16 columns (lanes of the l16 group), store
#pragma unroll
    for (int r = 0; r < 4; r++) {
      float ls = lsum[r];
      ls += __shfl_xor(ls, 1);
      ls += __shfl_xor(ls, 2);
      ls += __shfl_xor(ls, 4);
      ls += __shfl_xor(ls, 8);
      const float iv = 1.0f / ls;
      bf16* op = out + (rowbase + qrow_c + r) * EMB + h * HD;
      op[0 + l16] = (bf16)(o0[r] * iv);
      op[16 + l16] = (bf16)(o1[r] * iv);
      op[32 + l16] = (bf16)(o2[r] * iv);
      op[48 + l16] = (bf16)(o3[r] * iv);
    }
  }
}

// ---------------------------------------------------------------------------
extern "C" void kernel_launch(void* const* d_in, const int* in_sizes, int n_in,
                              void* d_out, int out_size, void* d_ws, size_t ws_size,
                              hipStream_t stream) {
  const float* x     = (const float*)d_in[0];
  const float* Wq    = (const float*)d_in[1];
  const float* Wk    = (const float*)d_in[2];
  const float* Wv    = (const float*)d_in[3];
  const float* Wo    = (const float*)d_in[4];
  const float* ln1_g = (const float*)d_in[5];
  const float* ln1_b = (const float*)d_in[6];
  const float* ln2_g = (const float*)d_in[7];
  const float* ln2_b = (const float*)d_in[8];
  const float* W1    = (const float*)d_in[9];
  const float* b1    = (const float*)d_in[10];
  const float* W2    = (const float*)d_in[11];
  const float* b2    = (const float*)d_in[12];
  float* out = (float*)d_out;  // doubles as x2 (post-attention residual state)

  bf16* p = (bf16*)d_ws;
  bf16* wqkv_t = p;                 p += (size_t)QKVN * EMB;   // [3072][1024]
  bf16* wo_t   = p;                 p += (size_t)EMB * EMB;    // [1024][1024]
  bf16* w1_t   = p;                 p += (size_t)FFN * EMB;    // [4096][1024]
  bf16* w2_t   = p;                 p += (size_t)EMB * FFN;    // [1024][4096]
  bf16* h      = p;                 p += (size_t)ROWS * EMB;   // LN out; aliased as vt
  bf16* qkv    = p;                 p += (size_t)ROWS * QKVN;  // [8192][3072]
  bf16* attn_o = p;                 p += (size_t)ROWS * EMB;   // [8192][1024]
  bf16* ffn1   = p;                 /* [8192][4096] */
  bf16* vt     = h;  // alias: h (LN1 out) is dead once QKV GEMM completes

  // 1) weight transpose-casts.  Wq/Wk/Wv/Wo in ONE launch (contiguous dests:
  //    wqkv_t then wo_t); Wq folds the 1/8 attention scale.
  transpose_cast4<<<dim3(32, 32, 4), 256, 0, stream>>>(Wq, Wk, Wv, Wo, wqkv_t);
  transpose_cast<<<dim3(128, 32), 256, 0, stream>>>(W1, w1_t, EMB, FFN, 1.0f);
  transpose_cast<<<dim3(32, 128), 256, 0, stream>>>(W2, w2_t, FFN, EMB, 1.0f);

  // 2) LN1 (wave-per-row)
  layernorm_bf16<<<ROWS / 4, 256, 0, stream>>>(x, ln1_g, ln1_b, h);

  // 3) fused QKV projection
  gemm_bt<0, QKVN, EMB><<<dim3(QKVN / 128, ROWS / 128), 256, 0, stream>>>(
      h, wqkv_t, qkv, nullptr, nullptr);

  // 4) V transpose (h is dead now; vt aliases it)
  v_transpose<<<dim3(SEQ / 32, HD / 32, 64), 256, 0, stream>>>(qkv, vt);

  // 5) causal flash attention (1D grid, XCD-aware decode)
  flash_attn<<<1024, 256, 0, stream>>>(qkv, vt, attn_o);

  // 6) output projection + residual -> x2 (in d_out)
  gemm_bt<1, EMB, EMB><<<dim3(EMB / 128, ROWS / 128), 256, 0, stream>>>(
      attn_o, wo_t, out, nullptr, x);

  // 7) LN2 (overwrites vt alias — flash is done)
  layernorm_bf16<<<ROWS / 4, 256, 0, stream>>>(out, ln2_g, ln2_b, h);

  // 8) FFN up + GELU (tanh form)
  gemm_bt<2, FFN, EMB><<<dim3(FFN / 128, ROWS / 128), 256, 0, stream>>>(
      h, w1_t, ffn1, b1, nullptr);

  // 9) FFN down + bias + residual -> final out
  gemm_bt<3, EMB, FFN><<<dim3(EMB / 128, ROWS / 128), 256, 0, stream>>>(
      ffn1, w2_t, out, b2, out);
}